// Round 2
// baseline (383.446 us; speedup 1.0000x reference)
//
#include <hip/hip_runtime.h>

// FFTConvNet: out[b,o] = IFFT2( M · sum_i X^[(b+8)%16, i] · W^[(o+32)%64, i] ) + bias[o]
// (fftshift with no axes shifts ALL dims -> batch roll by 8, Cout roll by 32; Cin rolls cancel.)
// Disk mask fy^2+fx^2 <= 900 -> only half-spectrum rectangle fy in [-30,30] (61), fx in [0,30] (31).
// Workspace requirement: (8126464 + 2*3872768)*4 = 63,488,000 bytes.

#define PI2_128 0.04908738521234052f  // 2*pi/128
#define NF 1891                       // 61*31

// ---------------- K1: row DFT ----------------
// x[bi][y][x] -> X1[bi][c=2fx+ri][y], fx 0..30 (re/im rows), e^{-2pi i fx x/128}
__global__ __launch_bounds__(256) void k1_rowdft(const float* __restrict__ x,
                                                 float* __restrict__ X1) {
  // [x][y] transpose, row stride 128 (full y range!), y-quad swizzled by s(xx)=(xx^(xx>>2))&31
  __shared__ __align__(16) float imgT[128 * 128];
  const int bi = blockIdx.x;
  const int tid = threadIdx.x;
  const float* img = x + (size_t)bi * (128 * 128);

  for (int j = tid; j < 128 * 32; j += 256) {
    int y = j >> 5, xq = j & 31;
    float4 v = *(const float4*)(img + y * 128 + xq * 4);
    int yq = y >> 2, yr = y & 3;
    float vv[4] = {v.x, v.y, v.z, v.w};
#pragma unroll
    for (int u = 0; u < 4; ++u) {
      int xx = xq * 4 + u;
      int sx = (xx ^ (xx >> 2)) & 31;
      imgT[xx * 128 + ((yq ^ sx) << 2) + yr] = vv[u];
    }
  }
  __syncthreads();

  const int cg = tid >> 5;   // 0..7  -> fx0 = 4*cg
  const int yg = tid & 31;   // 0..31 -> y0 = 4*yg
  const int fx0 = cg * 4;
  const int y0 = yg * 4;

  float pc[4], ps[4], stc[4], sts[4];
#pragma unroll
  for (int f = 0; f < 4; ++f) {
    __sincosf((float)(fx0 + f) * PI2_128, &sts[f], &stc[f]);
    pc[f] = 1.f;
    ps[f] = 0.f;
  }
  float o_r[4][4] = {{0.f}}, o_i[4][4] = {{0.f}};
  for (int k = 0; k < 128; ++k) {
    int sk = (k ^ (k >> 2)) & 31;
    float4 bv = *(const float4*)(&imgT[k * 128 + ((yg ^ sk) << 2)]);
    float bf[4] = {bv.x, bv.y, bv.z, bv.w};
#pragma unroll
    for (int f = 0; f < 4; ++f) {
      float c = pc[f], s = ps[f];
#pragma unroll
      for (int yy = 0; yy < 4; ++yy) {
        o_r[f][yy] += bf[yy] * c;
        o_i[f][yy] -= bf[yy] * s;
      }
      pc[f] = c * stc[f] - s * sts[f];
      ps[f] = s * stc[f] + c * sts[f];
    }
  }
  float* X1s = X1 + (size_t)bi * (62 * 128);
#pragma unroll
  for (int f = 0; f < 4; ++f) {
    int fx = fx0 + f;
    if (fx < 31) {
      *(float4*)(X1s + (2 * fx) * 128 + y0) =
          make_float4(o_r[f][0], o_r[f][1], o_r[f][2], o_r[f][3]);
      *(float4*)(X1s + (2 * fx + 1) * 128 + y0) =
          make_float4(o_i[f][0], o_i[f][1], o_i[f][2], o_i[f][3]);
    }
  }
}

// ---------------- K2: column DFT + disk mask ----------------
// X1[bi][c][y] -> X2[bi][f=t*31+fx] (float2), t=fy+30, e^{-2pi i fy y/128}, zeros off-disk
__global__ __launch_bounds__(256) void k2_coldft(const float* __restrict__ X1,
                                                 float* __restrict__ X2) {
  __shared__ __align__(16) float Bl[128 * 68];  // [y][c] (62 cols used, stride 68)
  const int bi = blockIdx.x;
  const int tid = threadIdx.x;
  const float* X1s = X1 + (size_t)bi * (62 * 128);
  for (int j = tid; j < 62 * 128; j += 256) {
    int c = j >> 7, y = j & 127;
    Bl[y * 68 + c] = X1s[j];
  }
  __syncthreads();
  const int tg = tid >> 3;  // 0..31 -> t0 = 2*tg
  const int fg = tid & 7;   // 0..7  -> fx0 = 4*fg
  const int t0 = tg * 2;
  const int fx0 = fg * 4;

  float pc[2], ps[2], stc[2], sts[2];
#pragma unroll
  for (int tt = 0; tt < 2; ++tt) {
    float fy = (float)(t0 + tt - 30);
    __sincosf(fy * PI2_128, &sts[tt], &stc[tt]);
    pc[tt] = 1.f;
    ps[tt] = 0.f;
  }
  float o_r[2][4] = {{0.f}}, o_i[2][4] = {{0.f}};
  for (int y = 0; y < 128; ++y) {
    float4 b0 = *(const float4*)(&Bl[y * 68 + 2 * fx0]);
    float4 b1 = *(const float4*)(&Bl[y * 68 + 2 * fx0 + 4]);
    float ar[4] = {b0.x, b0.z, b1.x, b1.z};
    float ai[4] = {b0.y, b0.w, b1.y, b1.w};
#pragma unroll
    for (int tt = 0; tt < 2; ++tt) {
      float c = pc[tt], s = ps[tt];
#pragma unroll
      for (int ff = 0; ff < 4; ++ff) {
        o_r[tt][ff] += ar[ff] * c + ai[ff] * s;
        o_i[tt][ff] += ai[ff] * c - ar[ff] * s;
      }
      pc[tt] = c * stc[tt] - s * sts[tt];
      ps[tt] = s * stc[tt] + c * sts[tt];
    }
  }
  float2* X2c = (float2*)X2 + (size_t)bi * NF;
#pragma unroll
  for (int tt = 0; tt < 2; ++tt) {
    int t = t0 + tt;
    if (t >= 61) continue;
    int fy = t - 30;
#pragma unroll
    for (int ff = 0; ff < 4; ++ff) {
      int fx = fx0 + ff;
      if (fx >= 31) continue;
      bool keep = (fy * fy + fx * fx) <= 900;
      X2c[t * 31 + fx] =
          keep ? make_float2(o_r[tt][ff], o_i[tt][ff]) : make_float2(0.f, 0.f);
    }
  }
}

// ---------------- K3: per-frequency channel mix ----------------
// F[f][b][o] = sum_i X2[(b+8)&15, i][f] * W^[(o+32)&63, i][f]
__global__ __launch_bounds__(256) void k3_mix(const float* __restrict__ X2,
                                              const float* __restrict__ w,
                                              float* __restrict__ F) {
  __shared__ float2 tw[128];
  __shared__ __align__(16) float2 X2t[4][16][16];  // [fi][il][b(shifted already)]
  __shared__ __align__(16) float2 Wt[4][16][64];   // [fi][il][o]
  const int tid = threadIdx.x;
  const int f0 = blockIdx.x * 4;
  if (tid < 128) {
    float sv, cv;
    __sincosf((float)tid * PI2_128, &sv, &cv);
    tw[tid] = make_float2(cv, sv);
  }
  const int fi_g = tid >> 6;  // 0..3 (this thread's freq)
  const int lane = tid & 63;
  const int bt = lane >> 4;  // 0..3  -> b0 = 4*bt
  const int ot = lane & 15;  // 0..15 -> o0 = 4*ot
  const int fg = f0 + fi_g;
  float o_r[4][4] = {{0.f}}, o_i[4][4] = {{0.f}};
  __syncthreads();

  for (int itile = 0; itile < 4; ++itile) {
    for (int j = tid; j < 1024; j += 256) {  // 4 freq * 16 i * 16 b
      int fi = j >> 8, rem = j & 255;
      int il = rem >> 4, b = rem & 15;
      int f = f0 + fi;
      if (f < NF) {
        int i = itile * 16 + il;
        int bs = (b + 8) & 15;  // batch fftshift
        X2t[fi][il][b] = ((const float2*)X2)[(size_t)(bs * 64 + i) * NF + f];
      }
    }
    for (int j = tid; j < 4096; j += 256) {  // 4 freq * 16 i * 64 o
      int fi = j >> 10, rem = j & 1023;
      int il = rem >> 6, o = rem & 63;
      int f = f0 + fi;
      if (f < NF) {
        int t = f / 31;
        int fx = f - t * 31;
        int fy = t - 30;
        int i = itile * 16 + il;
        int op = (o + 32) & 63;  // Cout fftshift
        const float* wp = w + (size_t)(op * 64 + i) * 9;
        float re = 0.f, im = 0.f;
#pragma unroll
        for (int ky = 0; ky < 3; ++ky)
#pragma unroll
          for (int kx = 0; kx < 3; ++kx) {
            int m = (fy * ky + fx * kx) & 127;
            float wv = wp[ky * 3 + kx];
            re += wv * tw[m].x;
            im -= wv * tw[m].y;
          }
        Wt[fi][il][o] = make_float2(re, im);
      }
    }
    __syncthreads();
    for (int il = 0; il < 16; ++il) {
      float2 xv[4], wv[4];
#pragma unroll
      for (int jb = 0; jb < 4; ++jb) xv[jb] = X2t[fi_g][il][bt * 4 + jb];
#pragma unroll
      for (int jo = 0; jo < 4; ++jo) wv[jo] = Wt[fi_g][il][ot * 4 + jo];
#pragma unroll
      for (int jb = 0; jb < 4; ++jb)
#pragma unroll
        for (int jo = 0; jo < 4; ++jo) {
          o_r[jb][jo] += xv[jb].x * wv[jo].x - xv[jb].y * wv[jo].y;
          o_i[jb][jo] += xv[jb].x * wv[jo].y + xv[jb].y * wv[jo].x;
        }
    }
    __syncthreads();
  }
  if (fg < NF) {
    float2* Fc = (float2*)F + (size_t)fg * 1024;
#pragma unroll
    for (int jb = 0; jb < 4; ++jb) {
      int b = bt * 4 + jb;
#pragma unroll
      for (int jo = 0; jo < 4; ++jo)
        Fc[b * 64 + ot * 4 + jo] = make_float2(o_r[jb][jo], o_i[jb][jo]);
    }
  }
}

// ---------------- K4: inverse column DFT ----------------
// G[fx][b][o][y] = sum_t F[t*31+fx][b][o] * e^{+2pi i (t-30) y/128}
__global__ __launch_bounds__(256, 1) void k4_invcol(const float* __restrict__ F,
                                                    float* __restrict__ G) {
  __shared__ __align__(16) float2 Fl[61][128];  // [t][bo], bo = b*8+oj
  const int fx = blockIdx.x >> 3;
  const int o0 = (blockIdx.x & 7) * 8;
  const int tid = threadIdx.x;
  const float2* Fc = (const float2*)F;
  for (int j = tid; j < 61 * 128; j += 256) {
    int t = j >> 7, bo = j & 127;
    int b = bo >> 3, oj = bo & 7;
    Fl[t][bo] = Fc[(size_t)(t * 31 + fx) * 1024 + b * 64 + o0 + oj];
  }
  __syncthreads();
  const int bog = tid >> 4;  // 0..15 -> bo0 = 8*bog
  const int yg = tid & 15;   // 0..15 -> y0 = 8*yg
  const int bo0 = bog * 8, y0 = yg * 8;

  float pc[8], ps[8], stc[8], sts[8];
#pragma unroll
  for (int u = 0; u < 8; ++u) {
    int y = y0 + u;
    __sincosf((float)y * PI2_128, &sts[u], &stc[u]);  // step e^{+2pi i y/128}
    int m = (-30 * y) & 127;                          // init at fy = -30 (int-reduced)
    __sincosf((float)m * PI2_128, &ps[u], &pc[u]);
  }
  float g_r[8][8] = {{0.f}}, g_i[8][8] = {{0.f}};
  for (int t = 0; t < 61; ++t) {
    float bf[16];
    *(float4*)&bf[0] = *(const float4*)(&Fl[t][bo0]);
    *(float4*)&bf[4] = *(const float4*)(&Fl[t][bo0 + 2]);
    *(float4*)&bf[8] = *(const float4*)(&Fl[t][bo0 + 4]);
    *(float4*)&bf[12] = *(const float4*)(&Fl[t][bo0 + 6]);
#pragma unroll
    for (int v = 0; v < 8; ++v) {
      float fr = bf[2 * v], fi = bf[2 * v + 1];
#pragma unroll
      for (int u = 0; u < 8; ++u) {
        g_r[v][u] += fr * pc[u] - fi * ps[u];
        g_i[v][u] += fr * ps[u] + fi * pc[u];
      }
    }
#pragma unroll
    for (int u = 0; u < 8; ++u) {
      float c = pc[u], s = ps[u];
      pc[u] = c * stc[u] - s * sts[u];
      ps[u] = s * stc[u] + c * sts[u];
    }
  }
  float2* Gc = (float2*)G;
#pragma unroll
  for (int v = 0; v < 8; ++v) {
    int bo = bo0 + v, b = bo >> 3, oj = bo & 7;
    size_t base = ((size_t)(fx * 16 + b) * 64 + o0 + oj) * 128 + y0;
#pragma unroll
    for (int u = 0; u < 8; u += 2) {
      *(float4*)(&Gc[base + u]) =
          make_float4(g_r[v][u], g_i[v][u], g_r[v][u + 1], g_i[v][u + 1]);
    }
  }
}

// ---------------- K5: inverse row DFT (Hermitian) + bias ----------------
// out[b][o][y][x] = (1/N^2)( Gr[0][y] + sum_{fx=1..30} 2(Gr cos - Gi sin) ) + bias[o]
__global__ __launch_bounds__(256) void k5_invrow(const float* __restrict__ G,
                                                 const float* __restrict__ bias,
                                                 float* __restrict__ out) {
  __shared__ __align__(16) float U[61 * 128];  // [c][y]
  __shared__ __align__(16) float V[61 * 128];  // [c][x]
  const int b = blockIdx.x >> 6;
  const int o = blockIdx.x & 63;
  const int tid = threadIdx.x;
  const float2* Gc = (const float2*)G;
  for (int j = tid; j < 31 * 128; j += 256) {
    int fx = j >> 7, y = j & 127;
    float2 v = Gc[((size_t)(fx * 16 + b) * 64 + o) * 128 + y];
    U[fx * 128 + y] = v.x;
    if (fx >= 1) U[(30 + fx) * 128 + y] = v.y;
  }
  const float sc1 = 1.f / 16384.f;
  for (int j = tid; j < 61 * 128; j += 256) {
    int c = j >> 7, xx = j & 127;
    float val;
    if (c == 0) {
      val = sc1;
    } else if (c <= 30) {
      int m = (c * xx) & 127;
      float sv, cv;
      __sincosf((float)m * PI2_128, &sv, &cv);
      val = 2.f * sc1 * cv;
    } else {
      int fx = c - 30;
      int m = (fx * xx) & 127;
      float sv, cv;
      __sincosf((float)m * PI2_128, &sv, &cv);
      val = -2.f * sc1 * sv;
    }
    V[c * 128 + xx] = val;
  }
  __syncthreads();
  const int ygr = tid >> 4, xg = tid & 15;
  const int y0 = ygr * 8, x0 = xg * 8;
  float acc[8][8] = {{0.f}};
  for (int c = 0; c < 61; ++c) {
    float uf[8], vf[8];
    *(float4*)&uf[0] = *(const float4*)(&U[c * 128 + y0]);
    *(float4*)&uf[4] = *(const float4*)(&U[c * 128 + y0 + 4]);
    *(float4*)&vf[0] = *(const float4*)(&V[c * 128 + x0]);
    *(float4*)&vf[4] = *(const float4*)(&V[c * 128 + x0 + 4]);
#pragma unroll
    for (int jy = 0; jy < 8; ++jy)
#pragma unroll
      for (int jx = 0; jx < 8; ++jx) acc[jy][jx] += uf[jy] * vf[jx];
  }
  const float bo_ = bias[o];
  float* op = out + ((size_t)(b * 64 + o) * 128) * 128;
#pragma unroll
  for (int jy = 0; jy < 8; ++jy) {
    *(float4*)(op + (y0 + jy) * 128 + x0) =
        make_float4(acc[jy][0] + bo_, acc[jy][1] + bo_, acc[jy][2] + bo_, acc[jy][3] + bo_);
    *(float4*)(op + (y0 + jy) * 128 + x0 + 4) =
        make_float4(acc[jy][4] + bo_, acc[jy][5] + bo_, acc[jy][6] + bo_, acc[jy][7] + bo_);
  }
}

extern "C" void kernel_launch(void* const* d_in, const int* in_sizes, int n_in,
                              void* d_out, int out_size, void* d_ws, size_t ws_size,
                              hipStream_t stream) {
  (void)in_sizes; (void)n_in; (void)out_size; (void)ws_size;
  const float* x = (const float*)d_in[0];
  const float* w = (const float*)d_in[1];
  const float* bias = (const float*)d_in[2];
  float* out = (float*)d_out;

  // ws layout (floats): X1 [0, 8126464) ; X2 [8126464, +3872768) ; F next ; G reuses X1 region.
  float* X1 = (float*)d_ws;
  float* X2 = X1 + 8126464;  // 1024*62*128
  float* F = X2 + 3872768;   // 1891*1024*2
  float* G = X1;             // X1 dead after K2; same size (8126464 floats)

  k1_rowdft<<<1024, 256, 0, stream>>>(x, X1);
  k2_coldft<<<1024, 256, 0, stream>>>(X1, X2);
  k3_mix<<<473, 256, 0, stream>>>(X2, w, F);
  k4_invcol<<<248, 256, 0, stream>>>(F, G);
  k5_invrow<<<1024, 256, 0, stream>>>(G, bias, out);
}